// Round 7
// baseline (223.982 us; speedup 1.0000x reference)
//
#include <hip/hip_runtime.h>

typedef unsigned short u16;
typedef unsigned long long u64;
typedef __attribute__((ext_vector_type(8))) short short8;   // bf16x8 MFMA fragment
typedef __attribute__((ext_vector_type(4))) float f32x4;

#define MFMA16(A,B,C) __builtin_amdgcn_mfma_f32_16x16x32_bf16(A,B,C,0,0,0)
#define NEG_INF_F (-4294967295.0f)

#define Bsz 8
#define Lsz 2048
#define Dsz 128

__device__ __forceinline__ u16 f2bf(float f){
  union { float f; unsigned u; } v; v.f = f;
  unsigned u = v.u;
  return (u16)((u + 0x7fffu + ((u >> 16) & 1u)) >> 16);
}
__device__ __forceinline__ float bf2f(u16 h){
  union { float f; unsigned u; } v; v.u = ((unsigned)h) << 16;
  return v.f;
}

// ---------------- projection: y = x @ W^T + b, Lorentz map -----------------
// z=0: q~ narrow*(2/scale) bf16 (d0=0), tq = -(2/scale)*t  fp32
// z=1: k~ narrow bf16 (d0=0),           tk = t             fp32
// z=2: v  TRANSPOSED [B][128][2048] hi+lo bf16 + per-block partial sums fp32
#define LPX 136   // bf16 pitch
#define LPY 133   // f32 pitch

__global__ __launch_bounds__(256) void proj_kernel(
    const float* __restrict__ xq, const float* __restrict__ xk, const float* __restrict__ xv,
    const float* __restrict__ Wq, const float* __restrict__ Wk, const float* __restrict__ Wv,
    const float* __restrict__ bq, const float* __restrict__ bk, const float* __restrict__ bv,
    const float* __restrict__ sq, const float* __restrict__ sk, const float* __restrict__ sv,
    const float* __restrict__ attn_scale,
    u16* __restrict__ qout, u16* __restrict__ kout,
    u16* __restrict__ vthi, u16* __restrict__ vtlo,
    float* __restrict__ tqo, float* __restrict__ tko,
    float* __restrict__ vpart)
{
  const int z = blockIdx.z;
  const float* x  = (z == 0) ? xq : (z == 1) ? xk : xv;
  const float* W  = (z == 0) ? Wq : (z == 1) ? Wk : Wv;
  const float* bb = (z == 0) ? bq : (z == 1) ? bk : bv;
  const float* ss = (z == 0) ? sq : (z == 1) ? sk : sv;

  __shared__ u16  xl[64 * LPX];
  __shared__ u16  wl[128 * LPX];
  __shared__ float yl[64 * LPY];
  __shared__ float scl[64];
  __shared__ float tml[64];

  const int t = threadIdx.x;
  const long row0 = (long)blockIdx.x * 64;

  for (int i = t; i < 128 * 128; i += 256) {
    int r = i >> 7, c = i & 127;
    wl[r * LPX + c] = f2bf(W[i]);
  }
  for (int i = t; i < 64 * 128; i += 256) {
    int r = i >> 7, c = i & 127;
    xl[r * LPX + c] = f2bf(x[row0 * 128 + i]);
  }
  __syncthreads();

  const int l = t & 63, wid = t >> 6;
  const int qr = l & 15, g = l >> 4;
  const int r0 = wid * 16;

  short8 af[4];
#pragma unroll
  for (int ks = 0; ks < 4; ks++)
    af[ks] = *(const short8*)&xl[(r0 + qr) * LPX + ks * 32 + g * 8];

  f32x4 acc[8];
#pragma unroll
  for (int jt = 0; jt < 8; jt++) acc[jt] = (f32x4){0.f, 0.f, 0.f, 0.f};

#pragma unroll
  for (int ks = 0; ks < 4; ks++) {
#pragma unroll
    for (int jt = 0; jt < 8; jt++) {
      short8 bfr = *(const short8*)&wl[(jt * 16 + qr) * LPX + ks * 32 + g * 8];
      acc[jt] = MFMA16(af[ks], bfr, acc[jt]);
    }
  }

  // bias + per-row squared-sum entirely in fragment registers
  float bbv[8];
#pragma unroll
  for (int jt = 0; jt < 8; jt++) bbv[jt] = bb[jt * 16 + qr];

  float ssq[4] = {0.f, 0.f, 0.f, 0.f};
#pragma unroll
  for (int jt = 0; jt < 8; jt++)
#pragma unroll
    for (int r = 0; r < 4; r++) {
      float yv = acc[jt][r] + bbv[jt];
      acc[jt][r] = yv;
      float s2 = yv * yv;
      if (jt == 0) s2 = (qr == 0) ? 0.f : s2;   // exclude d=0
      ssq[r] += s2;
    }
#pragma unroll
  for (int r = 0; r < 4; r++) {
    ssq[r] += __shfl_xor(ssq[r], 1);
    ssq[r] += __shfl_xor(ssq[r], 2);
    ssq[r] += __shfl_xor(ssq[r], 4);
    ssq[r] += __shfl_xor(ssq[r], 8);
  }

  const float es = __expf(ss[0]);
  const float fold = 2.0f / attn_scale[0];

  float tvv[4], sclv[4];
#pragma unroll
  for (int r = 0; r < 4; r++) {
    float y0 = __shfl(acc[0][r], l & 48);     // qr==0 lane of same g: d=0 value
    float tv = es / (1.0f + __expf(-y0)) + 1.1f;
    tvv[r] = tv;
    sclv[r] = sqrtf((tv * tv - 1.0f) / ssq[r]);
  }
  if (qr == 0) {
#pragma unroll
    for (int r = 0; r < 4; r++) {
      tml[r0 + g * 4 + r] = tvv[r];
      scl[r0 + g * 4 + r] = sclv[r];
    }
  }
#pragma unroll
  for (int jt = 0; jt < 8; jt++)
#pragma unroll
    for (int r = 0; r < 4; r++)
      yl[(r0 + g * 4 + r) * LPY + jt * 16 + qr] = acc[jt][r];
  __syncthreads();

  const long gbase = row0 * 128;
  if (z == 0) {
    for (int i = t; i < 64 * 128; i += 256) {
      int r = i >> 7, d = i & 127;
      float v = (d == 0) ? 0.f : yl[r * LPY + d] * scl[r] * fold;
      qout[gbase + i] = f2bf(v);
    }
    if (t < 64) tqo[row0 + t] = -tml[t] * fold;
  } else if (z == 1) {
    for (int i = t; i < 64 * 128; i += 256) {
      int r = i >> 7, d = i & 127;
      float v = (d == 0) ? 0.f : yl[r * LPY + d] * scl[r];
      kout[gbase + i] = f2bf(v);
    }
    if (t < 64) tko[row0 + t] = tml[t];
  } else {
    const int b = (int)(row0 >> 11);
    const int lpos = (int)(row0 & 2047);
    for (int i = t; i < 128 * 64; i += 256) {
      int d = i >> 6, r = i & 63;
      float v = (d == 0) ? tml[r] : yl[r * LPY + d] * scl[r];
      u16 hi = f2bf(v);
      float lo = v - bf2f(hi);
      long idx = ((long)(b * 128 + d)) * 2048 + lpos + r;
      vthi[idx] = hi;
      vtlo[idx] = f2bf(lo);
    }
    if (t < 128) {
      float s = 0.f;
      for (int r = 0; r < 64; r++)
        s += (t == 0) ? tml[r] : yl[r * LPY + t] * scl[r];
      int blk = (int)((row0 >> 6) & 31);
      vpart[((long)(b * 32 + blk)) * 128 + t] = s;
    }
  }
}

// ---------------- pack key-padding mask into 64-bit words -------------------
__global__ __launch_bounds__(256) void pack_mask_kernel(
    const int* __restrict__ mask, u64* __restrict__ pmask)
{
  int w = blockIdx.x * 256 + threadIdx.x;
  if (w >= Bsz * 32) return;
  int b = w >> 5, kt = w & 31;
  u64 word = 0;
  for (int i = 0; i < 64; i++)
    word |= (u64)(mask[b * 2048 + kt * 64 + i] != 0) << i;
  pmask[w] = word;
}

// ---------------- deterministic v-sum reduce --------------------------------
__global__ __launch_bounds__(128) void vreduce_kernel(
    const float* __restrict__ vpart, float* __restrict__ vsum)
{
  int i = blockIdx.x * 128 + threadIdx.x;   // 0 .. 1023
  int b = i >> 7, d = i & 127;
  float s = 0.f;
  for (int j = 0; j < 32; j++) s += vpart[((long)(b * 32 + j)) * 128 + d];
  vsum[i] = s;
}

// ---------------- flash attention + Lorentz epilogue ------------------------
// 8 waves per block, TWO strips per block (sA=127-p, sB=p) so every block has
// ~33 tiles: waves 0..kA-1 split strip A, kA..7 split strip B, kA proportional
// -> all wave durations ~4-4.6 tiles -> sustained 16 waves/CU, no drain.
// Software-pipelined (K register rotation + V-hi hoist), spill-free; per-wave
// double-buffered P LDS; per-strip LSE merge. Batch pinned to XCD (b = blk&7).
__global__ __launch_bounds__(512, 4) void flash_kernel(
    const u16* __restrict__ qb, const u16* __restrict__ kb,
    const u16* __restrict__ vthi, const u16* __restrict__ vtlo,
    const float* __restrict__ tq, const float* __restrict__ tk,
    const u64* __restrict__ pmask, const float* __restrict__ vsum,
    float* __restrict__ out)
{
  // aliased: per-wave double P buffers (8*4608 B) during loop / merge buf after
  __shared__ __attribute__((aligned(16))) char smem[8 * 2 * 16 * 72 * 2];  // 36864 B
  __shared__ float mL[8][16], lL[8][16];
  __shared__ float ssqL[2][16][17];
  __shared__ float rdenL[2][16];

  float (*mrg)[16 * 66] = (float (*)[16 * 66])smem;   // [wave][q*66 + d]

  const int t = threadIdx.x;
  const int w = t >> 6, l = t & 63;
  const int blk = blockIdx.x;
  const int b = blk & 7;                    // batch == XCD (round-robin dispatch)
  const int p = blk >> 3;                   // 0..63 strip-pair index
  const int sA = 127 - p, sB = p;
  const int nktA = ((sA * 16 + 15) >> 6) + 1;
  const int nktB = ((sB * 16 + 15) >> 6) + 1;
  const int Tt = nktA + nktB;
  int kA = (8 * nktA + (Tt >> 1)) / Tt;
  kA = kA < 1 ? 1 : (kA > 7 ? 7 : kA);

  const bool inA = (w < kA);
  const int s  = inA ? sA : sB;
  const int K  = inA ? kA : 8 - kA;
  const int wk = inA ? w : w - kA;
  const int q0 = s * 16;
  const int qr = l & 15, g = l >> 4;
  const int qg = q0 + qr;

  u16* plb = (u16*)smem + w * (2 * 16 * 72);  // double buffer base (u16 units)

  const u16* qptr = qb + ((long)(b * 2048 + q0 + qr)) * 128 + g * 8;
  short8 qf[4];
#pragma unroll
  for (int ks = 0; ks < 4; ks++) qf[ks] = *(const short8*)(qptr + ks * 32);

  const float tqv = tq[b * 2048 + qg];      // already -(2/scale)*t_q

  // this wave's k-tile range within its strip
  const int nkt = inA ? nktA : nktB;
  const int t0 = (nkt * wk) / K;
  const int t1 = (nkt * (wk + 1)) / K;

  float m = NEG_INF_F, lsum = 0.f;          // lsum: per-lane partial (k-split)
  f32x4 acc[8];
#pragma unroll
  for (int dt = 0; dt < 8; dt++) acc[dt] = (f32x4){0.f, 0.f, 0.f, 0.f};

  // K-tile fragments in registers, rotated each iteration
  short8 kreg[4][4];
  auto loadK = [&](int kt) {
    const int k0 = kt << 6;
#pragma unroll
    for (int tt = 0; tt < 4; tt++) {
      const u16* kp = kb + ((long)(b * 2048 + k0 + tt * 16 + qr)) * 128 + g * 8;
#pragma unroll
      for (int ks = 0; ks < 4; ks++)
        kreg[tt][ks] = *(const short8*)(kp + ks * 32);
    }
  };
  if (t0 < t1) loadK(t0);

  for (int kt = t0; kt < t1; kt++) {
    const int k0 = kt << 6;

    // issue mask + time-value loads early (land during QK MFMAs)
    const u64 mw = pmask[b * 32 + kt];
    f32x4 tkv[4];
#pragma unroll
    for (int tt = 0; tt < 4; tt++)
      tkv[tt] = *(const f32x4*)(tk + b * 2048 + k0 + tt * 16 + g * 4);

    // QK^T from current K registers
    f32x4 sv4[4];
#pragma unroll
    for (int tt = 0; tt < 4; tt++) {
      sv4[tt] = (f32x4){0.f, 0.f, 0.f, 0.f};
#pragma unroll
      for (int ks = 0; ks < 4; ks++)
        sv4[tt] = MFMA16(kreg[tt][ks], qf[ks], sv4[tt]);
    }

    // rotate: issue next tile's K loads now; they fly under softmax+PV
    if (kt + 1 < t1) loadK(kt + 1);

    // hoist V-hi (h=0) loads: fly during the softmax VALU chain
    const long vbase = ((long)(b * 128 + qr)) * 2048 + k0 + g * 8;
    short8 vh0[8];
#pragma unroll
    for (int dt = 0; dt < 8; dt++)
      vh0[dt] = *(const short8*)(vthi + vbase + (long)dt * 16 * 2048);

    const bool bndry = (k0 + 63 > q0);

    float p4[4][4];
    float tmax = NEG_INF_F;
#pragma unroll
    for (int tt = 0; tt < 4; tt++) {
#pragma unroll
      for (int r = 0; r < 4; r++) {
        int kl = tt * 16 + g * 4 + r;
        float val = sv4[tt][r] + tqv * tkv[tt][r];   // exact fp32 time product
        bool bad = ((mw >> kl) & 1ull) != 0ull;
        if (bndry) bad |= (k0 + kl > qg);
        val = bad ? NEG_INF_F : val;
        p4[tt][r] = val;
        tmax = fmaxf(tmax, val);
      }
    }
    tmax = fmaxf(tmax, __shfl_xor(tmax, 16));
    tmax = fmaxf(tmax, __shfl_xor(tmax, 32));

    float mn = fmaxf(m, tmax);
    float rr = __expf(m - mn);
    m = mn;

    float ts = 0.f;
#pragma unroll
    for (int tt = 0; tt < 4; tt++)
#pragma unroll
      for (int r = 0; r < 4; r++) {
        float pv = __expf(p4[tt][r] - mn);
        p4[tt][r] = pv;
        ts += pv;
      }

    // P -> private LDS, double-buffered (breaks WAR dep between tiles)
    u16* pl = plb + (kt & 1) * (16 * 72);
#pragma unroll
    for (int tt = 0; tt < 4; tt++) {
      u64 wv = (u64)f2bf(p4[tt][0])
             | ((u64)f2bf(p4[tt][1]) << 16)
             | ((u64)f2bf(p4[tt][2]) << 32)
             | ((u64)f2bf(p4[tt][3]) << 48);
      *(u64*)&pl[qr * 72 + tt * 16 + g * 4] = wv;
    }

    lsum = lsum * rr + ts;                  // per-lane partial; reduced after loop
#pragma unroll
    for (int dt = 0; dt < 8; dt++) {
      acc[dt][0] *= rr; acc[dt][1] *= rr; acc[dt][2] *= rr; acc[dt][3] *= rr;
    }

    // PV: h=0 uses preloaded V-hi; lo + h=1 inline
    {
      short8 pf0 = *(const short8*)&pl[qr * 72 + g * 8];
      short8 pf1 = *(const short8*)&pl[qr * 72 + 32 + g * 8];
      __builtin_amdgcn_s_setprio(1);
#pragma unroll
      for (int dt = 0; dt < 8; dt++) {
        long voff = vbase + (long)dt * 16 * 2048;
        short8 vl0 = *(const short8*)(vtlo + voff);
        acc[dt] = MFMA16(vh0[dt], pf0, acc[dt]);
        acc[dt] = MFMA16(vl0, pf0, acc[dt]);
        short8 vh1 = *(const short8*)(vthi + voff + 32);
        short8 vl1 = *(const short8*)(vtlo + voff + 32);
        acc[dt] = MFMA16(vh1, pf1, acc[dt]);
        acc[dt] = MFMA16(vl1, pf1, acc[dt]);
      }
      __builtin_amdgcn_s_setprio(0);
    }
  }

  // finalize per-lane lsum partial: reduce across the 4-lane k-group
  lsum += __shfl_xor(lsum, 16);
  lsum += __shfl_xor(lsum, 32);

  // ---- two-phase per-strip merge: publish d 0..63, merge, then d 64..127 ----
  __syncthreads();
#pragma unroll
  for (int dt = 0; dt < 4; dt++)
    *(f32x4*)&mrg[w][qr * 66 + dt * 16 + g * 4] = acc[dt];
  if (g == 0) { mL[w][qr] = m; lL[w][qr] = lsum; }
  __syncthreads();

  // thread t: strip st = t>>8, q = (t>>4)&15, d-segment (t&15)*4
  const int st = t >> 8;
  const int q = (t >> 4) & 15, seg = t & 15;
  const int jw0 = st == 0 ? 0 : kA;
  const int jw1 = st == 0 ? kA : 8;
  const int q0s = (st == 0 ? sA : sB) * 16;

  float M = NEG_INF_F;
#pragma unroll
  for (int j = 0; j < 8; j++)
    if (j >= jw0 && j < jw1) M = fmaxf(M, mL[j][q]);
  const bool mrow = (M == NEG_INF_F);       // row fully masked -> uniform over ALL keys

  float wj[8];
  float L = 0.f;
#pragma unroll
  for (int j = 0; j < 8; j++) {
    float e = __expf(mL[j][q] - M);
    e = (j >= jw0 && j < jw1) ? e : 0.f;
    wj[j] = e;
    L += e * lL[j][q];
  }
  float invL = mrow ? 0.f : 1.0f / L;

  const float* vs = vsum + b * 128;
  float av[8];
  float pp = 0.f;
#pragma unroll
  for (int i = 0; i < 4; i++) {
    int d = seg * 4 + i;
    float O = 0.f;
#pragma unroll
    for (int j = 0; j < 8; j++) O += wj[j] * mrg[j][q * 66 + d];
    float a = mrow ? vs[d] * (1.0f / 2048.0f) : O * invL;
    av[i] = a;
    pp += (d == 0) ? -a * a : a * a;
  }
  __syncthreads();          // phase-0 reads done before overwrite
#pragma unroll
  for (int dt = 4; dt < 8; dt++)
    *(f32x4*)&mrg[w][qr * 66 + (dt - 4) * 16 + g * 4] = acc[dt];
  __syncthreads();
#pragma unroll
  for (int i = 0; i < 4; i++) {
    int d = seg * 4 + i;
    float O = 0.f;
#pragma unroll
    for (int j = 0; j < 8; j++) O += wj[j] * mrg[j][q * 66 + d];
    float a = mrow ? vs[64 + d] * (1.0f / 2048.0f) : O * invL;
    av[4 + i] = a;
    pp += a * a;
  }
  ssqL[st][q][seg] = pp;
  __syncthreads();
  if (t < 32) {
    int s2 = t >> 4, qq = t & 15;
    float lor = 0.f;
    for (int j = 0; j < 16; j++) lor += ssqL[s2][qq][j];
    rdenL[s2][qq] = 1.0f / sqrtf(fmaxf(fabsf(lor), 1e-8f));
  }
  __syncthreads();

  const float rd = rdenL[st][q];
  float* op = out + ((long)(b * 2048 + q0s + q)) * 128 + seg * 4;
  f32x4 o1, o2;
  o1[0] = av[0] * rd; o1[1] = av[1] * rd; o1[2] = av[2] * rd; o1[3] = av[3] * rd;
  o2[0] = av[4] * rd; o2[1] = av[5] * rd; o2[2] = av[6] * rd; o2[3] = av[7] * rd;
  *(f32x4*)op = o1;
  *(f32x4*)(op + 64) = o2;
}

// ---------------- launch ----------------------------------------------------
extern "C" void kernel_launch(void* const* d_in, const int* in_sizes, int n_in,
                              void* d_out, int out_size, void* d_ws, size_t ws_size,
                              hipStream_t stream)
{
  const float* query = (const float*)d_in[0];
  const float* key   = (const float*)d_in[1];
  const float* value = (const float*)d_in[2];
  const int*   mask  = (const int*)d_in[3];
  const float* Wq = (const float*)d_in[4];
  const float* bq = (const float*)d_in[5];
  const float* sq = (const float*)d_in[6];
  const float* Wk = (const float*)d_in[7];
  const float* bk = (const float*)d_in[8];
  const float* sk = (const float*)d_in[9];
  const float* Wv = (const float*)d_in[10];
  const float* bv = (const float*)d_in[11];
  const float* sv = (const float*)d_in[12];
  const float* attn_scale = (const float*)d_in[13];
  // d_in[14] = attn_bias: cancels in softmax, unused

  float* out = (float*)d_out;
  char* ws = (char*)d_ws;

  float* vsum  = (float*)ws;                        // 4 KB
  u64*   pmask = (u64*)(ws + 4096);                 // 2 KB (pad to 4 KB)
  float* tqa   = (float*)(ws + 8192);               // 64 KB
  float* tka   = (float*)(ws + 8192 + 65536);       // 64 KB
  float* vpart = (float*)(ws + 8192 + 131072);      // 128 KB
  char*  big   = ws + 8192 + 131072 + 131072;
  u16*   qbuf  = (u16*)big;                         // 4 MB
  u16*   kbuf  = qbuf + (size_t)16384 * 128;        // 4 MB
  u16*   vthi  = kbuf + (size_t)16384 * 128;        // 4 MB
  u16*   vtlo  = vthi + (size_t)16384 * 128;        // 4 MB

  proj_kernel<<<dim3(256, 1, 3), 256, 0, stream>>>(
      query, key, value, Wq, Wk, Wv, bq, bk, bv, sq, sk, sv, attn_scale,
      qbuf, kbuf, vthi, vtlo, tqa, tka, vpart);
  pack_mask_kernel<<<1, 256, 0, stream>>>(mask, pmask);
  vreduce_kernel<<<8, 128, 0, stream>>>(vpart, vsum);
  flash_kernel<<<512, 512, 0, stream>>>(
      qbuf, kbuf, vthi, vtlo, tqa, tka, pmask, vsum, out);
}

// Round 8
// 147.414 us; speedup vs baseline: 1.5194x; 1.5194x over previous
//
#include <hip/hip_runtime.h>

typedef unsigned short u16;
typedef unsigned long long u64;
typedef __attribute__((ext_vector_type(8))) short short8;   // bf16x8 MFMA fragment
typedef __attribute__((ext_vector_type(4))) float f32x4;

#define MFMA16(A,B,C) __builtin_amdgcn_mfma_f32_16x16x32_bf16(A,B,C,0,0,0)
#define NEG_INF_F (-4294967295.0f)

#define Bsz 8
#define Lsz 2048
#define Dsz 128

__device__ __forceinline__ u16 f2bf(float f){
  union { float f; unsigned u; } v; v.f = f;
  unsigned u = v.u;
  return (u16)((u + 0x7fffu + ((u >> 16) & 1u)) >> 16);
}
__device__ __forceinline__ float bf2f(u16 h){
  union { float f; unsigned u; } v; v.u = ((unsigned)h) << 16;
  return v.f;
}

// ---------------- projection: y = x @ W^T + b, Lorentz map -----------------
// z=0: q~ narrow*(2/scale) bf16 (d0=0), tq = -(2/scale)*t  fp32
// z=1: k~ narrow bf16 (d0=0),           tk = t             fp32
// z=2: v  TRANSPOSED [B][128][2048] hi+lo bf16 + per-block partial sums fp32
#define LPX 136   // bf16 pitch
#define LPY 133   // f32 pitch

__global__ __launch_bounds__(256) void proj_kernel(
    const float* __restrict__ xq, const float* __restrict__ xk, const float* __restrict__ xv,
    const float* __restrict__ Wq, const float* __restrict__ Wk, const float* __restrict__ Wv,
    const float* __restrict__ bq, const float* __restrict__ bk, const float* __restrict__ bv,
    const float* __restrict__ sq, const float* __restrict__ sk, const float* __restrict__ sv,
    const float* __restrict__ attn_scale,
    u16* __restrict__ qout, u16* __restrict__ kout,
    u16* __restrict__ vthi, u16* __restrict__ vtlo,
    float* __restrict__ tqo, float* __restrict__ tko,
    float* __restrict__ vpart)
{
  const int z = blockIdx.z;
  const float* x  = (z == 0) ? xq : (z == 1) ? xk : xv;
  const float* W  = (z == 0) ? Wq : (z == 1) ? Wk : Wv;
  const float* bb = (z == 0) ? bq : (z == 1) ? bk : bv;
  const float* ss = (z == 0) ? sq : (z == 1) ? sk : sv;

  __shared__ u16  xl[64 * LPX];
  __shared__ u16  wl[128 * LPX];
  __shared__ float yl[64 * LPY];
  __shared__ float scl[64];
  __shared__ float tml[64];

  const int t = threadIdx.x;
  const long row0 = (long)blockIdx.x * 64;

  for (int i = t; i < 128 * 128; i += 256) {
    int r = i >> 7, c = i & 127;
    wl[r * LPX + c] = f2bf(W[i]);
  }
  for (int i = t; i < 64 * 128; i += 256) {
    int r = i >> 7, c = i & 127;
    xl[r * LPX + c] = f2bf(x[row0 * 128 + i]);
  }
  __syncthreads();

  const int l = t & 63, wid = t >> 6;
  const int qr = l & 15, g = l >> 4;
  const int r0 = wid * 16;

  short8 af[4];
#pragma unroll
  for (int ks = 0; ks < 4; ks++)
    af[ks] = *(const short8*)&xl[(r0 + qr) * LPX + ks * 32 + g * 8];

  f32x4 acc[8];
#pragma unroll
  for (int jt = 0; jt < 8; jt++) acc[jt] = (f32x4){0.f, 0.f, 0.f, 0.f};

#pragma unroll
  for (int ks = 0; ks < 4; ks++) {
#pragma unroll
    for (int jt = 0; jt < 8; jt++) {
      short8 bfr = *(const short8*)&wl[(jt * 16 + qr) * LPX + ks * 32 + g * 8];
      acc[jt] = MFMA16(af[ks], bfr, acc[jt]);
    }
  }

  // bias + per-row squared-sum entirely in fragment registers
  float bbv[8];
#pragma unroll
  for (int jt = 0; jt < 8; jt++) bbv[jt] = bb[jt * 16 + qr];

  float ssq[4] = {0.f, 0.f, 0.f, 0.f};
#pragma unroll
  for (int jt = 0; jt < 8; jt++)
#pragma unroll
    for (int r = 0; r < 4; r++) {
      float yv = acc[jt][r] + bbv[jt];
      acc[jt][r] = yv;
      float s2 = yv * yv;
      if (jt == 0) s2 = (qr == 0) ? 0.f : s2;   // exclude d=0
      ssq[r] += s2;
    }
#pragma unroll
  for (int r = 0; r < 4; r++) {
    ssq[r] += __shfl_xor(ssq[r], 1);
    ssq[r] += __shfl_xor(ssq[r], 2);
    ssq[r] += __shfl_xor(ssq[r], 4);
    ssq[r] += __shfl_xor(ssq[r], 8);
  }

  const float es = __expf(ss[0]);
  const float fold = 2.0f / attn_scale[0];

  float tvv[4], sclv[4];
#pragma unroll
  for (int r = 0; r < 4; r++) {
    float y0 = __shfl(acc[0][r], l & 48);     // qr==0 lane of same g: d=0 value
    float tv = es / (1.0f + __expf(-y0)) + 1.1f;
    tvv[r] = tv;
    sclv[r] = sqrtf((tv * tv - 1.0f) / ssq[r]);
  }
  if (qr == 0) {
#pragma unroll
    for (int r = 0; r < 4; r++) {
      tml[r0 + g * 4 + r] = tvv[r];
      scl[r0 + g * 4 + r] = sclv[r];
    }
  }
#pragma unroll
  for (int jt = 0; jt < 8; jt++)
#pragma unroll
    for (int r = 0; r < 4; r++)
      yl[(r0 + g * 4 + r) * LPY + jt * 16 + qr] = acc[jt][r];
  __syncthreads();

  const long gbase = row0 * 128;
  if (z == 0) {
    for (int i = t; i < 64 * 128; i += 256) {
      int r = i >> 7, d = i & 127;
      float v = (d == 0) ? 0.f : yl[r * LPY + d] * scl[r] * fold;
      qout[gbase + i] = f2bf(v);
    }
    if (t < 64) tqo[row0 + t] = -tml[t] * fold;
  } else if (z == 1) {
    for (int i = t; i < 64 * 128; i += 256) {
      int r = i >> 7, d = i & 127;
      float v = (d == 0) ? 0.f : yl[r * LPY + d] * scl[r];
      kout[gbase + i] = f2bf(v);
    }
    if (t < 64) tko[row0 + t] = tml[t];
  } else {
    const int b = (int)(row0 >> 11);
    const int lpos = (int)(row0 & 2047);
    for (int i = t; i < 128 * 64; i += 256) {
      int d = i >> 6, r = i & 63;
      float v = (d == 0) ? tml[r] : yl[r * LPY + d] * scl[r];
      u16 hi = f2bf(v);
      float lo = v - bf2f(hi);
      long idx = ((long)(b * 128 + d)) * 2048 + lpos + r;
      vthi[idx] = hi;
      vtlo[idx] = f2bf(lo);
    }
    if (t < 128) {
      float s = 0.f;
      for (int r = 0; r < 64; r++)
        s += (t == 0) ? tml[r] : yl[r * LPY + t] * scl[r];
      int blk = (int)((row0 >> 6) & 31);
      vpart[((long)(b * 32 + blk)) * 128 + t] = s;
    }
  }
}

// ---------------- pack key-padding mask: one wave per 64-bit word -----------
__global__ __launch_bounds__(256) void pack_mask_kernel(
    const int* __restrict__ mask, u64* __restrict__ pmask)
{
  int gt = blockIdx.x * 256 + threadIdx.x;
  int w = gt >> 6;                     // word index 0..255
  int lane = gt & 63;
  if (w >= Bsz * 32) return;
  u64 word = __ballot(mask[w * 64 + lane] != 0);
  if (lane == 0) pmask[w] = word;
}

// ---------------- deterministic v-sum reduce --------------------------------
__global__ __launch_bounds__(128) void vreduce_kernel(
    const float* __restrict__ vpart, float* __restrict__ vsum)
{
  int i = blockIdx.x * 128 + threadIdx.x;   // 0 .. 1023
  int b = i >> 7, d = i & 127;
  float s = 0.f;
  for (int j = 0; j < 32; j++) s += vpart[((long)(b * 32 + j)) * 128 + d];
  vsum[i] = s;
}

// ---------------- flash attention + Lorentz epilogue ------------------------
// 8 waves per block, TWO strips per block (sA=127-p, sB=p) so every block has
// ~33 tiles: waves 0..kA-1 split strip A, kA..7 split strip B, kA proportional
// -> all wave durations ~4-4.6 tiles, all block durations equal (no drain).
// __launch_bounds__(512,2): 256-VGPR budget (proven spill-free at ~124); if
// the allocation stays <=128 two blocks/CU co-reside -> 4 waves/SIMD sustained.
// Software-pipelined (K register rotation + V-hi hoist); per-wave
// double-buffered P LDS; per-strip LSE merge. Batch pinned to XCD (b = blk&7).
__global__ __launch_bounds__(512, 2) void flash_kernel(
    const u16* __restrict__ qb, const u16* __restrict__ kb,
    const u16* __restrict__ vthi, const u16* __restrict__ vtlo,
    const float* __restrict__ tq, const float* __restrict__ tk,
    const u64* __restrict__ pmask, const float* __restrict__ vsum,
    float* __restrict__ out)
{
  // aliased: per-wave double P buffers (8*4608 B) during loop / merge buf after
  __shared__ __attribute__((aligned(16))) char smem[8 * 2 * 16 * 72 * 2];  // 36864 B
  __shared__ float mL[8][16], lL[8][16];
  __shared__ float ssqL[2][16][17];
  __shared__ float rdenL[2][16];

  float (*mrg)[16 * 66] = (float (*)[16 * 66])smem;   // [wave][q*66 + d]

  const int t = threadIdx.x;
  const int w = t >> 6, l = t & 63;
  const int blk = blockIdx.x;
  const int b = blk & 7;                    // batch == XCD (round-robin dispatch)
  const int p = blk >> 3;                   // 0..63 strip-pair index
  const int sA = 127 - p, sB = p;
  const int nktA = ((sA * 16 + 15) >> 6) + 1;
  const int nktB = ((sB * 16 + 15) >> 6) + 1;
  const int Tt = nktA + nktB;
  int kA = (8 * nktA + (Tt >> 1)) / Tt;
  kA = kA < 1 ? 1 : (kA > 7 ? 7 : kA);

  const bool inA = (w < kA);
  const int s  = inA ? sA : sB;
  const int K  = inA ? kA : 8 - kA;
  const int wk = inA ? w : w - kA;
  const int q0 = s * 16;
  const int qr = l & 15, g = l >> 4;
  const int qg = q0 + qr;

  u16* plb = (u16*)smem + w * (2 * 16 * 72);  // double buffer base (u16 units)

  const u16* qptr = qb + ((long)(b * 2048 + q0 + qr)) * 128 + g * 8;
  short8 qf[4];
#pragma unroll
  for (int ks = 0; ks < 4; ks++) qf[ks] = *(const short8*)(qptr + ks * 32);

  const float tqv = tq[b * 2048 + qg];      // already -(2/scale)*t_q

  // this wave's k-tile range within its strip
  const int nkt = inA ? nktA : nktB;
  const int t0 = (nkt * wk) / K;
  const int t1 = (nkt * (wk + 1)) / K;

  float m = NEG_INF_F, lsum = 0.f;          // lsum: per-lane partial (k-split)
  f32x4 acc[8];
#pragma unroll
  for (int dt = 0; dt < 8; dt++) acc[dt] = (f32x4){0.f, 0.f, 0.f, 0.f};

  // K-tile fragments in registers, rotated each iteration
  short8 kreg[4][4];
  auto loadK = [&](int kt) {
    const int k0 = kt << 6;
#pragma unroll
    for (int tt = 0; tt < 4; tt++) {
      const u16* kp = kb + ((long)(b * 2048 + k0 + tt * 16 + qr)) * 128 + g * 8;
#pragma unroll
      for (int ks = 0; ks < 4; ks++)
        kreg[tt][ks] = *(const short8*)(kp + ks * 32);
    }
  };
  if (t0 < t1) loadK(t0);

  for (int kt = t0; kt < t1; kt++) {
    const int k0 = kt << 6;

    // issue mask + time-value loads early (land during QK MFMAs)
    const u64 mw = pmask[b * 32 + kt];
    f32x4 tkv[4];
#pragma unroll
    for (int tt = 0; tt < 4; tt++)
      tkv[tt] = *(const f32x4*)(tk + b * 2048 + k0 + tt * 16 + g * 4);

    // QK^T from current K registers
    f32x4 sv4[4];
#pragma unroll
    for (int tt = 0; tt < 4; tt++) {
      sv4[tt] = (f32x4){0.f, 0.f, 0.f, 0.f};
#pragma unroll
      for (int ks = 0; ks < 4; ks++)
        sv4[tt] = MFMA16(kreg[tt][ks], qf[ks], sv4[tt]);
    }

    // rotate: issue next tile's K loads now; they fly under softmax+PV
    if (kt + 1 < t1) loadK(kt + 1);

    // hoist V-hi (h=0) loads: fly during the softmax VALU chain
    const long vbase = ((long)(b * 128 + qr)) * 2048 + k0 + g * 8;
    short8 vh0[8];
#pragma unroll
    for (int dt = 0; dt < 8; dt++)
      vh0[dt] = *(const short8*)(vthi + vbase + (long)dt * 16 * 2048);

    const bool bndry = (k0 + 63 > q0);

    float p4[4][4];
    float tmax = NEG_INF_F;
#pragma unroll
    for (int tt = 0; tt < 4; tt++) {
#pragma unroll
      for (int r = 0; r < 4; r++) {
        int kl = tt * 16 + g * 4 + r;
        float val = sv4[tt][r] + tqv * tkv[tt][r];   // exact fp32 time product
        bool bad = ((mw >> kl) & 1ull) != 0ull;
        if (bndry) bad |= (k0 + kl > qg);
        val = bad ? NEG_INF_F : val;
        p4[tt][r] = val;
        tmax = fmaxf(tmax, val);
      }
    }
    tmax = fmaxf(tmax, __shfl_xor(tmax, 16));
    tmax = fmaxf(tmax, __shfl_xor(tmax, 32));

    float mn = fmaxf(m, tmax);
    float rr = __expf(m - mn);
    m = mn;

    float ts = 0.f;
#pragma unroll
    for (int tt = 0; tt < 4; tt++)
#pragma unroll
      for (int r = 0; r < 4; r++) {
        float pv = __expf(p4[tt][r] - mn);
        p4[tt][r] = pv;
        ts += pv;
      }

    // P -> private LDS, double-buffered (breaks WAR dep between tiles)
    u16* pl = plb + (kt & 1) * (16 * 72);
#pragma unroll
    for (int tt = 0; tt < 4; tt++) {
      u64 wv = (u64)f2bf(p4[tt][0])
             | ((u64)f2bf(p4[tt][1]) << 16)
             | ((u64)f2bf(p4[tt][2]) << 32)
             | ((u64)f2bf(p4[tt][3]) << 48);
      *(u64*)&pl[qr * 72 + tt * 16 + g * 4] = wv;
    }

    lsum = lsum * rr + ts;                  // per-lane partial; reduced after loop
#pragma unroll
    for (int dt = 0; dt < 8; dt++) {
      acc[dt][0] *= rr; acc[dt][1] *= rr; acc[dt][2] *= rr; acc[dt][3] *= rr;
    }

    // PV: h=0 uses preloaded V-hi; lo + h=1 inline
    {
      short8 pf0 = *(const short8*)&pl[qr * 72 + g * 8];
      short8 pf1 = *(const short8*)&pl[qr * 72 + 32 + g * 8];
      __builtin_amdgcn_s_setprio(1);
#pragma unroll
      for (int dt = 0; dt < 8; dt++) {
        long voff = vbase + (long)dt * 16 * 2048;
        short8 vl0 = *(const short8*)(vtlo + voff);
        acc[dt] = MFMA16(vh0[dt], pf0, acc[dt]);
        acc[dt] = MFMA16(vl0, pf0, acc[dt]);
        short8 vh1 = *(const short8*)(vthi + voff + 32);
        short8 vl1 = *(const short8*)(vtlo + voff + 32);
        acc[dt] = MFMA16(vh1, pf1, acc[dt]);
        acc[dt] = MFMA16(vl1, pf1, acc[dt]);
      }
      __builtin_amdgcn_s_setprio(0);
    }
  }

  // finalize per-lane lsum partial: reduce across the 4-lane k-group
  lsum += __shfl_xor(lsum, 16);
  lsum += __shfl_xor(lsum, 32);

  // ---- two-phase per-strip merge: publish d 0..63, merge, then d 64..127 ----
  __syncthreads();
#pragma unroll
  for (int dt = 0; dt < 4; dt++)
    *(f32x4*)&mrg[w][qr * 66 + dt * 16 + g * 4] = acc[dt];
  if (g == 0) { mL[w][qr] = m; lL[w][qr] = lsum; }
  __syncthreads();

  // thread t: strip st = t>>8, q = (t>>4)&15, d-segment (t&15)*4
  const int st = t >> 8;
  const int q = (t >> 4) & 15, seg = t & 15;
  const int jw0 = st == 0 ? 0 : kA;
  const int jw1 = st == 0 ? kA : 8;
  const int q0s = (st == 0 ? sA : sB) * 16;

  float M = NEG_INF_F;
#pragma unroll
  for (int j = 0; j < 8; j++)
    if (j >= jw0 && j < jw1) M = fmaxf(M, mL[j][q]);
  const bool mrow = (M == NEG_INF_F);       // row fully masked -> uniform over ALL keys

  float wj[8];
  float L = 0.f;
#pragma unroll
  for (int j = 0; j < 8; j++) {
    float e = __expf(mL[j][q] - M);
    e = (j >= jw0 && j < jw1) ? e : 0.f;
    wj[j] = e;
    L += e * lL[j][q];
  }
  float invL = mrow ? 0.f : 1.0f / L;

  const float* vs = vsum + b * 128;
  float av[8];
  float pp = 0.f;
#pragma unroll
  for (int i = 0; i < 4; i++) {
    int d = seg * 4 + i;
    float O = 0.f;
#pragma unroll
    for (int j = 0; j < 8; j++) O += wj[j] * mrg[j][q * 66 + d];
    float a = mrow ? vs[d] * (1.0f / 2048.0f) : O * invL;
    av[i] = a;
    pp += (d == 0) ? -a * a : a * a;
  }
  __syncthreads();          // phase-0 reads done before overwrite
#pragma unroll
  for (int dt = 4; dt < 8; dt++)
    *(f32x4*)&mrg[w][qr * 66 + (dt - 4) * 16 + g * 4] = acc[dt];
  __syncthreads();
#pragma unroll
  for (int i = 0; i < 4; i++) {
    int d = seg * 4 + i;
    float O = 0.f;
#pragma unroll
    for (int j = 0; j < 8; j++) O += wj[j] * mrg[j][q * 66 + d];
    float a = mrow ? vs[64 + d] * (1.0f / 2048.0f) : O * invL;
    av[4 + i] = a;
    pp += a * a;
  }
  ssqL[st][q][seg] = pp;
  __syncthreads();
  if (t < 32) {
    int s2 = t >> 4, qq = t & 15;
    float lor = 0.f;
    for (int j = 0; j < 16; j++) lor += ssqL[s2][qq][j];
    rdenL[s2][qq] = 1.0f / sqrtf(fmaxf(fabsf(lor), 1e-8f));
  }
  __syncthreads();

  const float rd = rdenL[st][q];
  float* op = out + ((long)(b * 2048 + q0s + q)) * 128 + seg * 4;
  f32x4 o1, o2;
  o1[0] = av[0] * rd; o1[1] = av[1] * rd; o1[2] = av[2] * rd; o1[3] = av[3] * rd;
  o2[0] = av[4] * rd; o2[1] = av[5] * rd; o2[2] = av[6] * rd; o2[7 - 7] = o2[0];
  o2[0] = av[4] * rd; o2[1] = av[5] * rd; o2[2] = av[6] * rd; o2[3] = av[7] * rd;
  *(f32x4*)op = o1;
  *(f32x4*)(op + 64) = o2;
}

// ---------------- launch ----------------------------------------------------
extern "C" void kernel_launch(void* const* d_in, const int* in_sizes, int n_in,
                              void* d_out, int out_size, void* d_ws, size_t ws_size,
                              hipStream_t stream)
{
  const float* query = (const float*)d_in[0];
  const float* key   = (const float*)d_in[1];
  const float* value = (const float*)d_in[2];
  const int*   mask  = (const int*)d_in[3];
  const float* Wq = (const float*)d_in[4];
  const float* bq = (const float*)d_in[5];
  const float* sq = (const float*)d_in[6];
  const float* Wk = (const float*)d_in[7];
  const float* bk = (const float*)d_in[8];
  const float* sk = (const float*)d_in[9];
  const float* Wv = (const float*)d_in[10];
  const float* bv = (const float*)d_in[11];
  const float* sv = (const float*)d_in[12];
  const float* attn_scale = (const float*)d_in[13];
  // d_in[14] = attn_bias: cancels in softmax, unused

  float* out = (float*)d_out;
  char* ws = (char*)d_ws;

  float* vsum  = (float*)ws;                        // 4 KB
  u64*   pmask = (u64*)(ws + 4096);                 // 2 KB (pad to 4 KB)
  float* tqa   = (float*)(ws + 8192);               // 64 KB
  float* tka   = (float*)(ws + 8192 + 65536);       // 64 KB
  float* vpart = (float*)(ws + 8192 + 131072);      // 128 KB
  char*  big   = ws + 8192 + 131072 + 131072;
  u16*   qbuf  = (u16*)big;                         // 4 MB
  u16*   kbuf  = qbuf + (size_t)16384 * 128;        // 4 MB
  u16*   vthi  = kbuf + (size_t)16384 * 128;        // 4 MB
  u16*   vtlo  = vthi + (size_t)16384 * 128;        // 4 MB

  proj_kernel<<<dim3(256, 1, 3), 256, 0, stream>>>(
      query, key, value, Wq, Wk, Wv, bq, bk, bv, sq, sk, sv, attn_scale,
      qbuf, kbuf, vthi, vtlo, tqa, tka, vpart);
  pack_mask_kernel<<<64, 256, 0, stream>>>(mask, pmask);
  vreduce_kernel<<<8, 128, 0, stream>>>(vpart, vsum);
  flash_kernel<<<512, 512, 0, stream>>>(
      qbuf, kbuf, vthi, vtlo, tqa, tka, pmask, vsum, out);
}